// Round 4
// baseline (208.051 us; speedup 1.0000x reference)
//
#include <hip/hip_runtime.h>
#include <stdint.h>

#define BS 16
#define KQ 8192
#define NTOT (BS + KQ)   // 8208
#define H 768
#define G 5
#define UPD 0.1f
#define FPAD 772         // LDS row stride (floats): 772%32==4 -> rotated banks, conflict-free
#define ROWS 4           // f rows per main block
#define LG2PID (768.0f * 1.8378770664093453f)   // common shift, cancels after max-subtract

// ---- output layout (floats) ----
#define SZ_BN   (BS*NTOT)        // 131328
#define SZ_BNG  (BS*NTOT*G)     // 656640
#define O_GLOGITS 0
#define O_GPROB   (SZ_BNG)
#define O_CTSLOG  (2*SZ_BNG)
#define O_ACC     (O_CTSLOG + SZ_BN)
#define O_NRM     (O_ACC + SZ_BN)
#define O_GLABEL  (O_NRM + G)
#define O_CLABEL  (O_GLABEL + SZ_BN)
#define O_CDIST   (O_CLABEL + SZ_BN)

// ---- workspace layout (float indices) ----
#define W_INV   0                    // G*H    exp(-lg_sigma2)
#define W_BB    (G*H)                // BS*G   lsm_g - 0.5(lg2piD + S + C + P - 2U)
#define W_CNT8  (W_BB + BS*G)        // 8*16 sharded counts
#define W_SUM8  (W_CNT8 + 128)      // 8*16 sharded sums
#define W_RMX8  (W_SUM8 + 128)      // 8*16 sharded row-max (uint-encoded)
#define W_DIAG  (W_RMX8 + 128)      // BS

__device__ __forceinline__ unsigned enc_f(float f) {
    unsigned u = __float_as_uint(f);
    return (u & 0x80000000u) ? ~u : (u | 0x80000000u);
}
__device__ __forceinline__ float dec_f(unsigned k) {
    return (k & 0x80000000u) ? __uint_as_float(k & 0x7fffffffu) : __uint_as_float(~k);
}

__device__ __forceinline__ float wave_red_sum(float v) {
    #pragma unroll
    for (int off = 32; off > 0; off >>= 1) v += __shfl_down(v, off, 64);
    return v;
}

__device__ __forceinline__ void gload_lds16(const float* g, float* l) {
    __builtin_amdgcn_global_load_lds(
        (const __attribute__((address_space(1))) void*)(g),
        (__attribute__((address_space(3))) void*)(l), 16, 0, 0);
}

// ---------------- Kernel 1: tiny prep (BB_bg, inv, zeros), grid 36 x 256 ----------------
__global__ __launch_bounds__(256) void prep_kernel(
    const float* __restrict__ sent_q, const float* __restrict__ mu,
    const float* __restrict__ lg,     const float* __restrict__ pi,
    float* __restrict__ ws)
{
    const int t = threadIdx.x;
    const int lane = t & 63;
    const int w = t >> 6;
    const int bx = blockIdx.x;

    if (bx < 20) {                       // 80 wave-tasks: BB_bg
        const int task = bx * 4 + w;     // = b*G + g
        const int b = task / G, g = task % G;
        float accP = 0.f, accU = 0.f, accC = 0.f, accS = 0.f;
        for (int h = lane; h < H; h += 64) {
            float qv  = sent_q[b*H + h];
            float lgv = lg[g*H + h];
            float m   = mu[g*H + h];
            float iv  = expf(-lgv);
            accP = fmaf(qv*qv, iv, accP);
            accU = fmaf(qv*m,  iv, accU);
            accC = fmaf(m*m,   iv, accC);
            accS += lgv;
        }
        accP = wave_red_sum(accP);
        accU = wave_red_sum(accU);
        accC = wave_red_sum(accC);
        accS = wave_red_sum(accS);
        if (lane == 0) {
            float mx = pi[0];
            #pragma unroll
            for (int gg = 1; gg < G; ++gg) mx = fmaxf(mx, pi[gg]);
            float s = 0.f;
            #pragma unroll
            for (int gg = 0; gg < G; ++gg) s += expf(pi[gg] - mx);
            float lse = mx + logf(s);
            ws[W_BB + task] =
                (pi[g] - lse) - 0.5f*(LG2PID + accS + accC + accP - 2.f*accU);
        }
    } else if (bx < 35) {                // 15 blocks: inv (G*H = 3840 = 15*256)
        const int i = (bx - 20) * 256 + t;
        ws[W_INV + i] = expf(-lg[i]);
    } else {                             // zero sharded accumulators (384 floats)
        for (int i = t; i < 384; i += 256) ws[W_CNT8 + i] = 0.f;
    }
}

// ---------------- Kernel 2: main fused compute (tv folded in) ----------------
// grid 2052 x 256. wave w = h-quarter AND owner of staged row w.
// lane p: b = p>>2, nl = p&3, n = bx*4 + nl.
__global__ __launch_bounds__(256, 8) void main_kernel(
    const float* __restrict__ sent_q,
    const float* __restrict__ sent_k,
    const float* __restrict__ queue,
    const float* __restrict__ rank_mean,
    const float* __restrict__ invp,
    const float* __restrict__ mup,
    const float* __restrict__ BBp,
    float* cnt8, float* sum8, unsigned* rmx8, float* diagp,
    float* __restrict__ out)
{
    __shared__ __align__(16) float fbuf[ROWS * FPAD];   // 12.3 KB
    __shared__ float red[64][21];                        // 5.25 KB, stride 21: conflict-free
    __shared__ float s_BB[BS*G];
    __shared__ float s_A2[ROWS*G];
    __shared__ float s_cnt[G], s_sum[G];

    const int t    = threadIdx.x;
    const int lane = t & 63;
    const int w    = t >> 6;            // wave id (wave-uniform)
    const int b    = lane >> 2;
    const int nl   = lane & 3;
    const int bx   = blockIdx.x;
    const int n    = bx * ROWS + nl;

    if (t < BS*G) s_BB[t] = BBp[t];
    if (t >= 160 && t < 160 + G) { s_cnt[t-160] = 0.f; s_sum[t-160] = 0.f; }

    // stage 4 f rows: wave w stages row w (coalesced, LDS dest = base + lane*16B)
    {
        const int rn = bx * ROWS + w;
        const float* src = ((rn < BS) ? (sent_k + rn*H) : (queue + (rn - BS)*H)) + lane*4;
        #pragma unroll
        for (int k = 0; k < 3; ++k)
            gload_lds16(src + k*256, &fbuf[w*FPAD + k*256]);
    }
    __syncthreads();

    // ---- tv: wave w computes A2 for its own row w from LDS
    {
        const float* frow = fbuf + w*FPAD;
        float Tp[G] = {0.f,0.f,0.f,0.f,0.f};
        float Vp[G] = {0.f,0.f,0.f,0.f,0.f};
        #pragma unroll
        for (int j = 0; j < 3; ++j) {
            const int h = j*256 + lane*4;
            const float4 fv = *reinterpret_cast<const float4*>(frow + h);
            const float fx2 = fv.x*fv.x, fy2 = fv.y*fv.y, fz2 = fv.z*fv.z, fw2 = fv.w*fv.w;
            #pragma unroll
            for (int g = 0; g < G; ++g) {
                const float4 iv = *reinterpret_cast<const float4*>(invp + g*H + h);
                const float4 mv = *reinterpret_cast<const float4*>(mup + g*H + h);
                Tp[g] = fmaf(fx2, iv.x, Tp[g]);
                Tp[g] = fmaf(fy2, iv.y, Tp[g]);
                Tp[g] = fmaf(fz2, iv.z, Tp[g]);
                Tp[g] = fmaf(fw2, iv.w, Tp[g]);
                Vp[g] = fmaf(fv.x, mv.x*iv.x, Vp[g]);
                Vp[g] = fmaf(fv.y, mv.y*iv.y, Vp[g]);
                Vp[g] = fmaf(fv.z, mv.z*iv.z, Vp[g]);
                Vp[g] = fmaf(fv.w, mv.w*iv.w, Vp[g]);
            }
        }
        #pragma unroll
        for (int g = 0; g < G; ++g) {
            float T = wave_red_sum(Tp[g]);
            float V = wave_red_sum(Vp[g]);
            if (lane == 0) s_A2[w*G + g] = 0.5f*T + V;
        }
    }

    // ---- main h-loop over this wave's quarter (192 floats)
    const int hu = __builtin_amdgcn_readfirstlane(w * 192);
    const float* qb = sent_q + b*H + hu;
    const float* fb = fbuf + nl*FPAD + hu;
    float sim = 0.f;
    float R[G] = {0.f, 0.f, 0.f, 0.f, 0.f};
    #pragma unroll 4
    for (int i = 0; i < 48; ++i) {
        const float4 qv = *reinterpret_cast<const float4*>(qb + i*4);
        const float4 fv = *reinterpret_cast<const float4*>(fb + i*4);
        float p0 = qv.x * fv.x;
        float p1 = qv.y * fv.y;
        float p2 = qv.z * fv.z;
        float p3 = qv.w * fv.w;
        sim += (p0 + p1) + (p2 + p3);
        #pragma unroll
        for (int g = 0; g < G; ++g) {
            const float* iv = invp + g*H + hu + i*4;   // wave-uniform -> scalar loads
            R[g] = fmaf(p3, iv[3], fmaf(p2, iv[2], fmaf(p1, iv[1], fmaf(p0, iv[0], R[g]))));
        }
    }

    // combine quarters
    if (w) {
        red[lane][(w-1)*6 + 0] = sim;
        #pragma unroll
        for (int g = 0; g < G; ++g) red[lane][(w-1)*6 + 1 + g] = R[g];
    }
    __syncthreads();   // covers red[] and s_A2[]

    if (w == 0) {
        #pragma unroll
        for (int qq = 0; qq < 3; ++qq) {
            sim += red[lane][qq*6];
            #pragma unroll
            for (int g = 0; g < G; ++g) R[g] += red[lane][qq*6 + 1 + g];
        }

        float lgt[G];
        #pragma unroll
        for (int g = 0; g < G; ++g)
            lgt[g] = s_BB[b*G + g] - s_A2[nl*G + g] + R[g];
        float mx = lgt[0];
        #pragma unroll
        for (int g = 1; g < G; ++g) mx = fmaxf(mx, lgt[g]);

        const int bn = b * NTOT + n;
        float e[G], se = 0.f;
        #pragma unroll
        for (int g = 0; g < G; ++g) {
            float ln = lgt[g] - mx;
            out[O_GLOGITS + (size_t)bn * G + g] = ln;
            e[g] = expf(ln);
            se += e[g];
        }
        int pred = 0; float bestp = -1.f;
        #pragma unroll
        for (int g = 0; g < G; ++g) {
            float pg = e[g] / se;
            out[O_GPROB + (size_t)bn * G + g] = pg;
            if (pg > bestp) { bestp = pg; pred = g; }   // first max
        }

        int cp = 0; float bd = fabsf(sim - rank_mean[0]);
        #pragma unroll
        for (int g = 1; g < G; ++g) {
            float d = fabsf(sim - rank_mean[g]);
            if (d < bd) { bd = d; cp = g; }             // first min
        }

        float cdist = floorf((sim + 1.0f) * 0.5f * (float)G);

        bool eyev = (n == b);
        bool gold = (n < BS) && (n == ((b + BS/2) & (BS - 1)));

        out[O_GLABEL + bn] = (eyev || gold) ? (float)(G - 1) : (float)cp;
        out[O_CLABEL + bn] = gold ? (float)(G - 1) : (float)pred;
        out[O_ACC    + bn] = eyev ? 0.f : sim;
        out[O_CDIST  + bn] = cdist;
        if (eyev) diagp[b] = sim;

        atomicAdd(&s_cnt[pred], 1.f);
        atomicAdd(&s_sum[pred], sim);

        // row max over the 4 nl lanes sharing b, then sharded global max
        float m4 = sim;
        m4 = fmaxf(m4, __shfl_down(m4, 2, 4));
        m4 = fmaxf(m4, __shfl_down(m4, 1, 4));
        if (nl == 0) atomicMax(&rmx8[(bx & 7) * 16 + b], enc_f(m4));
    }
    __syncthreads();
    if (t < G) {
        atomicAdd(&cnt8[(bx & 7) * 16 + t], s_cnt[t]);
        atomicAdd(&sum8[(bx & 7) * 16 + t], s_sum[t]);
    }
}

// ---------------- Kernel 3: cts_logits (float4) + new_rank_mean ----------------
__global__ __launch_bounds__(256) void final_kernel(
    const float* __restrict__ rank_mean,
    const float* __restrict__ cnt8, const float* __restrict__ sum8,
    const unsigned* __restrict__ rmx8, const float* __restrict__ diagp,
    float* __restrict__ out)
{
    const int i4 = blockIdx.x * 256 + threadIdx.x;
    if (i4 < G) {
        float c = 0.f, s = 0.f;
        #pragma unroll
        for (int j = 0; j < 8; ++j) { c += cnt8[j*16 + i4]; s += sum8[j*16 + i4]; }
        float cur = s / (c + 1e-12f);
        float u = (c != 0.f) ? 1.f : 0.f;
        out[O_NRM + i4] = (1.f - u * UPD) * rank_mean[i4] + u * UPD * cur;
    }
    if (i4 >= SZ_BN/4) return;
    const int i0 = i4 * 4;
    const int b  = i0 / NTOT;          // NTOT%4==0 -> all 4 share b
    const int n0 = i0 - b * NTOT;
    unsigned mk = 0u;
    #pragma unroll
    for (int j = 0; j < 8; ++j) mk = max(mk, rmx8[j*16 + b]);
    const float rm = dec_f(mk);
    float4 v = *reinterpret_cast<const float4*>(&out[O_ACC + i0]);
    if (b >= n0 && b < n0 + 4) {
        float d = diagp[b];
        int r = b - n0;
        if (r == 0) v.x = d; else if (r == 1) v.y = d;
        else if (r == 2) v.z = d; else v.w = d;
    }
    float4 o;
    o.x = v.x - rm; o.y = v.y - rm; o.z = v.z - rm; o.w = v.w - rm;
    *reinterpret_cast<float4*>(&out[O_CTSLOG + i0]) = o;
}

extern "C" void kernel_launch(void* const* d_in, const int* in_sizes, int n_in,
                              void* d_out, int out_size, void* d_ws, size_t ws_size,
                              hipStream_t stream) {
    const float* sent_q    = (const float*)d_in[0];
    const float* sent_k    = (const float*)d_in[1];
    const float* queue     = (const float*)d_in[2];
    const float* mu        = (const float*)d_in[3];
    const float* lg        = (const float*)d_in[4];
    const float* pi        = (const float*)d_in[5];
    const float* rank_mean = (const float*)d_in[6];
    float* out = (float*)d_out;
    float* ws  = (float*)d_ws;

    prep_kernel<<<36, 256, 0, stream>>>(sent_q, mu, lg, pi, ws);

    main_kernel<<<NTOT / ROWS, 256, 0, stream>>>(
        sent_q, sent_k, queue, rank_mean,
        ws + W_INV, mu, ws + W_BB,
        ws + W_CNT8, ws + W_SUM8,
        reinterpret_cast<unsigned*>(ws + W_RMX8), ws + W_DIAG,
        out);

    final_kernel<<<(SZ_BN/4 + 255) / 256, 256, 0, stream>>>(
        rank_mean, ws + W_CNT8, ws + W_SUM8,
        reinterpret_cast<const unsigned*>(ws + W_RMX8), ws + W_DIAG,
        out);
}

// Round 5
// 124.141 us; speedup vs baseline: 1.6759x; 1.6759x over previous
//
#include <hip/hip_runtime.h>
#include <stdint.h>

#define BS 16
#define KQ 8192
#define NTOT (BS + KQ)   // 8208
#define H 768
#define G 5
#define UPD 0.1f
#define FPAD 772         // LDS row stride (floats): 772%32==4 -> rotated banks, conflict-free
#define ROWS 4           // f rows per main block
#define LG2PID (768.0f * 1.8378770664093453f)   // common shift, cancels after max-subtract

// ---- output layout (floats) ----
#define SZ_BN   (BS*NTOT)        // 131328
#define SZ_BNG  (BS*NTOT*G)     // 656640
#define O_GLOGITS 0
#define O_GPROB   (SZ_BNG)
#define O_CTSLOG  (2*SZ_BNG)
#define O_ACC     (O_CTSLOG + SZ_BN)
#define O_NRM     (O_ACC + SZ_BN)
#define O_GLABEL  (O_NRM + G)
#define O_CLABEL  (O_GLABEL + SZ_BN)
#define O_CDIST   (O_CLABEL + SZ_BN)

// ---- workspace layout (float indices) ----
#define W_INV   0                    // G*H    exp(-lg_sigma2)
#define W_MSC   (G*H)                // G*H    mu * inv
#define W_BB    (2*G*H)              // BS*G   lsm_g - 0.5(lg2piD + S + C + P - 2U)
#define W_CNT8  (W_BB + BS*G)        // 8*16 sharded counts
#define W_SUM8  (W_CNT8 + 128)       // 8*16 sharded sums
#define W_RMX8  (W_SUM8 + 128)       // 8*16 sharded row-max (uint-encoded)
#define W_DIAG  (W_RMX8 + 128)       // BS

__device__ __forceinline__ unsigned enc_f(float f) {
    unsigned u = __float_as_uint(f);
    return (u & 0x80000000u) ? ~u : (u | 0x80000000u);
}
__device__ __forceinline__ float dec_f(unsigned k) {
    return (k & 0x80000000u) ? __uint_as_float(k & 0x7fffffffu) : __uint_as_float(~k);
}

__device__ __forceinline__ float wave_red_sum(float v) {
    #pragma unroll
    for (int off = 32; off > 0; off >>= 1) v += __shfl_down(v, off, 64);
    return v;
}

__device__ __forceinline__ void gload_lds16(const float* g, float* l) {
    __builtin_amdgcn_global_load_lds(
        (const __attribute__((address_space(1))) void*)(g),
        (__attribute__((address_space(3))) void*)(l), 16, 0, 0);
}

// ---------------- Kernel 1: tiny prep (BB_bg, inv, msc, zeros), grid 36 x 256 ----------------
__global__ __launch_bounds__(256) void prep_kernel(
    const float* __restrict__ sent_q, const float* __restrict__ mu,
    const float* __restrict__ lg,     const float* __restrict__ pi,
    float* __restrict__ ws)
{
    const int t = threadIdx.x;
    const int lane = t & 63;
    const int w = t >> 6;
    const int bx = blockIdx.x;

    if (bx < 20) {                       // 80 wave-tasks: BB_bg
        const int task = bx * 4 + w;     // = b*G + g
        const int b = task / G, g = task % G;
        float accP = 0.f, accU = 0.f, accC = 0.f, accS = 0.f;
        for (int h = lane; h < H; h += 64) {
            float qv  = sent_q[b*H + h];
            float lgv = lg[g*H + h];
            float m   = mu[g*H + h];
            float iv  = expf(-lgv);
            accP = fmaf(qv*qv, iv, accP);
            accU = fmaf(qv*m,  iv, accU);
            accC = fmaf(m*m,   iv, accC);
            accS += lgv;
        }
        accP = wave_red_sum(accP);
        accU = wave_red_sum(accU);
        accC = wave_red_sum(accC);
        accS = wave_red_sum(accS);
        if (lane == 0) {
            float mx = pi[0];
            #pragma unroll
            for (int gg = 1; gg < G; ++gg) mx = fmaxf(mx, pi[gg]);
            float s = 0.f;
            #pragma unroll
            for (int gg = 0; gg < G; ++gg) s += expf(pi[gg] - mx);
            float lse = mx + logf(s);
            ws[W_BB + task] =
                (pi[g] - lse) - 0.5f*(LG2PID + accS + accC + accP - 2.f*accU);
        }
    } else if (bx < 35) {                // 15 blocks: inv + msc (G*H = 3840 = 15*256)
        const int i = (bx - 20) * 256 + t;
        float iv = expf(-lg[i]);
        ws[W_INV + i] = iv;
        ws[W_MSC + i] = mu[i] * iv;
    } else {                             // zero sharded accumulators (384 floats)
        for (int i = t; i < 384; i += 256) ws[W_CNT8 + i] = 0.f;
    }
}

// ---------------- Kernel 2: main fused compute (tv folded in) ----------------
// grid 2052 x 256. wave w = h-quarter AND owner of staged row w.
// lane p: b = p>>2, nl = p&3, n = bx*4 + nl.
__global__ __launch_bounds__(256, 2) void main_kernel(
    const float* __restrict__ sent_q,
    const float* __restrict__ sent_k,
    const float* __restrict__ queue,
    const float* __restrict__ rank_mean,
    const float* __restrict__ invp,
    const float* __restrict__ mscp,
    const float* __restrict__ BBp,
    float* cnt8, float* sum8, unsigned* rmx8, float* diagp,
    float* __restrict__ out)
{
    __shared__ __align__(16) float fbuf[ROWS * FPAD];   // 12.3 KB
    __shared__ float red[64][21];                        // 5.25 KB, stride 21: conflict-free
    __shared__ float s_BB[BS*G];
    __shared__ float s_A2[ROWS*G];
    __shared__ float s_cnt[G], s_sum[G];

    const int t    = threadIdx.x;
    const int lane = t & 63;
    const int w    = t >> 6;            // wave id (wave-uniform)
    const int b    = lane >> 2;
    const int nl   = lane & 3;
    const int bx   = blockIdx.x;
    const int n    = bx * ROWS + nl;

    if (t < BS*G) s_BB[t] = BBp[t];
    if (t >= 160 && t < 160 + G) { s_cnt[t-160] = 0.f; s_sum[t-160] = 0.f; }

    // stage 4 f rows: wave w stages row w (coalesced, LDS dest = base + lane*16B)
    {
        const int rn = bx * ROWS + w;
        const float* src = ((rn < BS) ? (sent_k + rn*H) : (queue + (rn - BS)*H)) + lane*4;
        #pragma unroll
        for (int k = 0; k < 3; ++k)
            gload_lds16(src + k*256, &fbuf[w*FPAD + k*256]);
    }
    __syncthreads();

    // ---- tv: wave w computes A2 for its own row w from LDS (unroll 1: cap live regs)
    {
        const float* frow = fbuf + w*FPAD;
        float Tp[G] = {0.f,0.f,0.f,0.f,0.f};
        float Vp[G] = {0.f,0.f,0.f,0.f,0.f};
        #pragma unroll 1
        for (int j = 0; j < 3; ++j) {
            const int h = j*256 + lane*4;
            const float4 fv = *reinterpret_cast<const float4*>(frow + h);
            const float fx2 = fv.x*fv.x, fy2 = fv.y*fv.y, fz2 = fv.z*fv.z, fw2 = fv.w*fv.w;
            #pragma unroll
            for (int g = 0; g < G; ++g) {
                const float4 iv = *reinterpret_cast<const float4*>(invp + g*H + h);
                const float4 mv = *reinterpret_cast<const float4*>(mscp + g*H + h);
                Tp[g] = fmaf(fx2, iv.x, Tp[g]);
                Tp[g] = fmaf(fy2, iv.y, Tp[g]);
                Tp[g] = fmaf(fz2, iv.z, Tp[g]);
                Tp[g] = fmaf(fw2, iv.w, Tp[g]);
                Vp[g] = fmaf(fv.x, mv.x, Vp[g]);
                Vp[g] = fmaf(fv.y, mv.y, Vp[g]);
                Vp[g] = fmaf(fv.z, mv.z, Vp[g]);
                Vp[g] = fmaf(fv.w, mv.w, Vp[g]);
            }
        }
        #pragma unroll
        for (int g = 0; g < G; ++g) {
            float T = wave_red_sum(Tp[g]);
            float V = wave_red_sum(Vp[g]);
            if (lane == 0) s_A2[w*G + g] = 0.5f*T + V;
        }
    }

    // ---- main h-loop over this wave's quarter (192 floats)
    const int hu = __builtin_amdgcn_readfirstlane(w * 192);
    const float* qb = sent_q + b*H + hu;
    const float* fb = fbuf + nl*FPAD + hu;
    float sim = 0.f;
    float R[G] = {0.f, 0.f, 0.f, 0.f, 0.f};
    #pragma unroll 4
    for (int i = 0; i < 48; ++i) {
        const float4 qv = *reinterpret_cast<const float4*>(qb + i*4);
        const float4 fv = *reinterpret_cast<const float4*>(fb + i*4);
        float p0 = qv.x * fv.x;
        float p1 = qv.y * fv.y;
        float p2 = qv.z * fv.z;
        float p3 = qv.w * fv.w;
        sim += (p0 + p1) + (p2 + p3);
        #pragma unroll
        for (int g = 0; g < G; ++g) {
            const float* iv = invp + g*H + hu + i*4;   // wave-uniform -> scalar loads
            R[g] = fmaf(p3, iv[3], fmaf(p2, iv[2], fmaf(p1, iv[1], fmaf(p0, iv[0], R[g]))));
        }
    }

    // combine quarters
    if (w) {
        red[lane][(w-1)*6 + 0] = sim;
        #pragma unroll
        for (int g = 0; g < G; ++g) red[lane][(w-1)*6 + 1 + g] = R[g];
    }
    __syncthreads();   // covers red[] and s_A2[]

    if (w == 0) {
        #pragma unroll
        for (int qq = 0; qq < 3; ++qq) {
            sim += red[lane][qq*6];
            #pragma unroll
            for (int g = 0; g < G; ++g) R[g] += red[lane][qq*6 + 1 + g];
        }

        float lgt[G];
        #pragma unroll
        for (int g = 0; g < G; ++g)
            lgt[g] = s_BB[b*G + g] - s_A2[nl*G + g] + R[g];
        float mx = lgt[0];
        #pragma unroll
        for (int g = 1; g < G; ++g) mx = fmaxf(mx, lgt[g]);

        const int bn = b * NTOT + n;
        float e[G], se = 0.f;
        #pragma unroll
        for (int g = 0; g < G; ++g) {
            float ln = lgt[g] - mx;
            out[O_GLOGITS + (size_t)bn * G + g] = ln;
            e[g] = expf(ln);
            se += e[g];
        }
        int pred = 0; float bestp = -1.f;
        #pragma unroll
        for (int g = 0; g < G; ++g) {
            float pg = e[g] / se;
            out[O_GPROB + (size_t)bn * G + g] = pg;
            if (pg > bestp) { bestp = pg; pred = g; }   // first max
        }

        int cp = 0; float bd = fabsf(sim - rank_mean[0]);
        #pragma unroll
        for (int g = 1; g < G; ++g) {
            float d = fabsf(sim - rank_mean[g]);
            if (d < bd) { bd = d; cp = g; }             // first min
        }

        float cdist = floorf((sim + 1.0f) * 0.5f * (float)G);

        bool eyev = (n == b);
        bool gold = (n < BS) && (n == ((b + BS/2) & (BS - 1)));

        out[O_GLABEL + bn] = (eyev || gold) ? (float)(G - 1) : (float)cp;
        out[O_CLABEL + bn] = gold ? (float)(G - 1) : (float)pred;
        out[O_ACC    + bn] = eyev ? 0.f : sim;
        out[O_CDIST  + bn] = cdist;
        if (eyev) diagp[b] = sim;

        atomicAdd(&s_cnt[pred], 1.f);
        atomicAdd(&s_sum[pred], sim);

        // row max over the 4 nl lanes sharing b, then sharded global max
        float m4 = sim;
        m4 = fmaxf(m4, __shfl_down(m4, 2, 4));
        m4 = fmaxf(m4, __shfl_down(m4, 1, 4));
        if (nl == 0) atomicMax(&rmx8[(bx & 7) * 16 + b], enc_f(m4));
    }
    __syncthreads();
    if (t < G) {
        atomicAdd(&cnt8[(bx & 7) * 16 + t], s_cnt[t]);
        atomicAdd(&sum8[(bx & 7) * 16 + t], s_sum[t]);
    }
}

// ---------------- Kernel 3: cts_logits (float4) + new_rank_mean ----------------
__global__ __launch_bounds__(256) void final_kernel(
    const float* __restrict__ rank_mean,
    const float* __restrict__ cnt8, const float* __restrict__ sum8,
    const unsigned* __restrict__ rmx8, const float* __restrict__ diagp,
    float* __restrict__ out)
{
    const int i4 = blockIdx.x * 256 + threadIdx.x;
    if (i4 < G) {
        float c = 0.f, s = 0.f;
        #pragma unroll
        for (int j = 0; j < 8; ++j) { c += cnt8[j*16 + i4]; s += sum8[j*16 + i4]; }
        float cur = s / (c + 1e-12f);
        float u = (c != 0.f) ? 1.f : 0.f;
        out[O_NRM + i4] = (1.f - u * UPD) * rank_mean[i4] + u * UPD * cur;
    }
    if (i4 >= SZ_BN/4) return;
    const int i0 = i4 * 4;
    const int b  = i0 / NTOT;          // NTOT%4==0 -> all 4 share b
    const int n0 = i0 - b * NTOT;
    unsigned mk = 0u;
    #pragma unroll
    for (int j = 0; j < 8; ++j) mk = max(mk, rmx8[j*16 + b]);
    const float rm = dec_f(mk);
    float4 v = *reinterpret_cast<const float4*>(&out[O_ACC + i0]);
    if (b >= n0 && b < n0 + 4) {
        float d = diagp[b];
        int r = b - n0;
        if (r == 0) v.x = d; else if (r == 1) v.y = d;
        else if (r == 2) v.z = d; else v.w = d;
    }
    float4 o;
    o.x = v.x - rm; o.y = v.y - rm; o.z = v.z - rm; o.w = v.w - rm;
    *reinterpret_cast<float4*>(&out[O_CTSLOG + i0]) = o;
}

extern "C" void kernel_launch(void* const* d_in, const int* in_sizes, int n_in,
                              void* d_out, int out_size, void* d_ws, size_t ws_size,
                              hipStream_t stream) {
    const float* sent_q    = (const float*)d_in[0];
    const float* sent_k    = (const float*)d_in[1];
    const float* queue     = (const float*)d_in[2];
    const float* mu        = (const float*)d_in[3];
    const float* lg        = (const float*)d_in[4];
    const float* pi        = (const float*)d_in[5];
    const float* rank_mean = (const float*)d_in[6];
    float* out = (float*)d_out;
    float* ws  = (float*)d_ws;

    prep_kernel<<<36, 256, 0, stream>>>(sent_q, mu, lg, pi, ws);

    main_kernel<<<NTOT / ROWS, 256, 0, stream>>>(
        sent_q, sent_k, queue, rank_mean,
        ws + W_INV, ws + W_MSC, ws + W_BB,
        ws + W_CNT8, ws + W_SUM8,
        reinterpret_cast<unsigned*>(ws + W_RMX8), ws + W_DIAG,
        out);

    final_kernel<<<(SZ_BN/4 + 255) / 256, 256, 0, stream>>>(
        rank_mean, ws + W_CNT8, ws + W_SUM8,
        reinterpret_cast<const unsigned*>(ws + W_RMX8), ws + W_DIAG,
        out);
}